// Round 13
// baseline (356.245 us; speedup 1.0000x reference)
//
#include <hip/hip_runtime.h>
#include <hip/hip_bf16.h>

#define G_ 256
#define K_ 16
#define L_ 3
#define H_ 3
#define F_ 64
#define EMB_ 200
#define HID_ 256
#define N_ (G_*K_)          // 4096 nodes
#define E_ (G_*K_*(K_-1))   // 61440 edges

typedef __attribute__((ext_vector_type(8))) short short8;
typedef __attribute__((ext_vector_type(4))) float f32x4;

#define SELU_S 1.0507009873554804934193349852946f
#define SELU_SA (1.0507009873554804934193349852946f*1.6732632423543772848170429916717f)

// 5-op selu
__device__ __forceinline__ float selu_f(float x) {
  float e = __expf(x);
  float neg = fmaf(SELU_SA, e, -SELU_SA);
  float pos = SELU_S * x;
  return x > 0.f ? pos : neg;
}

__device__ __forceinline__ unsigned short f2bf(float x) {
  __hip_bfloat16 h = __float2bfloat16(x);
  return *reinterpret_cast<unsigned short*>(&h);
}

__device__ __forceinline__ unsigned int f2bf2(float a, float b) {
  float2 t; t.x = a; t.y = b;
  __hip_bfloat162 h = __float22bfloat162_rn(t);
  return *reinterpret_cast<unsigned int*>(&h);
}

__device__ __forceinline__ float bf2f(unsigned short u) {
  union { unsigned int i; float f; } v;
  v.i = ((unsigned int)u) << 16;
  return v.f;
}

// fea[n, 0:63] = elem_fea_in[n,:] @ W_init + b_init ; fea[n,63] = w[n]
__global__ __launch_bounds__(64) void init_embed(
    const float* __restrict__ fea_in, const float* __restrict__ W,
    const float* __restrict__ b, const float* __restrict__ wts,
    float* __restrict__ fea) {
  __shared__ float row[EMB_];
  int n = blockIdx.x;
  int j = threadIdx.x;
  for (int k = j; k < EMB_; k += 64) row[k] = fea_in[(size_t)n*EMB_ + k];
  __syncthreads();
  if (j < F_-1) {
    float s = b[j];
    for (int k = 0; k < EMB_; ++k) s = fmaf(row[k], W[k*(F_-1) + j], s);
    fea[(size_t)n*F_ + j] = s;
  } else {
    fea[(size_t)n*F_ + (F_-1)] = wts[n];
  }
}

// WcatT[lh][n][k] (bf16, n-major)
__global__ __launch_bounds__(256) void prep_wcat(
    const float* __restrict__ mg_W1, const float* __restrict__ mm_W1,
    unsigned short* __restrict__ WcatT) {
  int idx = blockIdx.x*256 + threadIdx.x;   // 9*1024*64
  int lh = idx >> 16;
  int n  = (idx >> 6) & 1023;
  int k  = idx & 63;
  const float* W = (n < 512) ? mg_W1 : mm_W1;
  int nn = n & 511;
  int r  = (nn < 256) ? k : (64 + k);
  int c  = nn & 255;
  WcatT[idx] = f2bf(W[(size_t)lh*(2*F_*HID_) + r*HID_ + c]);
}

// W2mT[lh][f][k] = bf16(mm_W2[lh][k][f])
__global__ __launch_bounds__(256) void prep_w2mt(
    const float* __restrict__ mm_W2, unsigned short* __restrict__ W2mT) {
  int idx = blockIdx.x*256 + threadIdx.x;   // 9*64*256
  int lh = idx >> 14;
  int f  = (idx >> 8) & 63;
  int k  = idx & 255;
  W2mT[idx] = f2bf(mm_W2[(size_t)lh*(HID_*F_) + k*F_ + f]);
}

// WcryT[n][k] (bf16, n-major, 1536 x 64)
__global__ __launch_bounds__(256) void prep_wcry(
    const float* __restrict__ cg_W1, const float* __restrict__ cm_W1,
    unsigned short* __restrict__ WcryT) {
  int idx = blockIdx.x*256 + threadIdx.x;   // 1536*64
  int n = idx >> 6, k = idx & 63;
  int h = n >> 9, r = n & 511;
  float v = (r < 256) ? cg_W1[(size_t)h*F_*HID_ + k*HID_ + r]
                      : cm_W1[(size_t)h*F_*HID_ + k*HID_ + (r - 256)];
  WcryT[idx] = f2bf(v);
}

// W2cT[h][f][k] = bf16(cm_W2[h][k][f])
__global__ __launch_bounds__(256) void prep_w2c(
    const float* __restrict__ cm_W2, unsigned short* __restrict__ W2cT) {
  int idx = blockIdx.x*256 + threadIdx.x;   // 3*64*256
  int h = idx >> 14;
  int f = (idx >> 8) & 63;
  int k = idx & 255;
  W2cT[idx] = f2bf(cm_W2[(size_t)h*HID_*F_ + k*F_ + f]);
}

// bias_e[l][3072]: h*1024 + [0,256)=mg_b1 ; [512,768)=mm_b1 ; else 0
// bias_c[1536]:    h*512  + [0,256)=cg_b1 ; [256,512)=cm_b1
__global__ __launch_bounds__(256) void prep_bias(
    const float* __restrict__ mg_b1, const float* __restrict__ mm_b1,
    const float* __restrict__ cg_b1, const float* __restrict__ cm_b1,
    float* __restrict__ bias_e, float* __restrict__ bias_c) {
  int idx = blockIdx.x*256 + threadIdx.x;
  if (idx < 9216) {
    int l = idx / 3072, c = idx - l*3072;
    int h = c >> 10, cc = c & 1023;
    int lh = l*H_ + h;
    float v = 0.f;
    if (cc < 256) v = mg_b1[lh*HID_ + cc];
    else if (cc >= 512 && cc < 768) v = mm_b1[lh*HID_ + (cc - 512)];
    bias_e[idx] = v;
  } else if (idx < 9216 + 1536) {
    int c = idx - 9216;
    int h = c >> 9, cc = c & 511;
    bias_c[c] = (cc < 256) ? cg_b1[h*HID_ + cc] : cm_b1[h*HID_ + (cc - 256)];
  }
}

// fea_nxt = cur (f32 copy, float4)
__global__ __launch_bounds__(256) void copy_fea(
    const float* __restrict__ in, float* __restrict__ out) {
  int i = blockIdx.x*256 + threadIdx.x;
  ((float4*)out)[i] = ((const float4*)in)[i];
}

// ---------------------------------------------------------------------------
// Fully fused edge phase, 512 threads, grid (G_, H_). LDS ~29 KB -> 4 blk/CU.
// Two-pass PQ GEMM over one 16x512 LDS buffer:
//   P1: gate-half GEMM -> PQs ; P2: gate dot + wp precompute + msg-bias load
//   P3: msg-half GEMM (overwrite PQs) + 16-thr softmax ; P4: msg MFMA + accum.
// ---------------------------------------------------------------------------
__global__ __launch_bounds__(512, 8) void edge_fused(
    const float* __restrict__ fea, const unsigned short* __restrict__ WcatT,
    const float* __restrict__ bias_e, const unsigned short* __restrict__ W2T,
    const float* __restrict__ mg_W2, const float* __restrict__ mg_b2,
    const float* __restrict__ m_pow, const float* __restrict__ mm_b2,
    const float* __restrict__ wts, float* __restrict__ fea_nxt, int l) {
  __shared__ __align__(16) unsigned short feaS[16][72];
  __shared__ __align__(16) unsigned short PQs[16][520];  // P|Q halves x256, skew 8
  __shared__ float bs[512];
  __shared__ float w2g[256];
  __shared__ float gred[240][2];
  __shared__ float gateA[240];
  __shared__ float accum[16][68];
  __shared__ float sumat[16];
  __shared__ float wp[16];
  int t = threadIdx.x;
  int g = blockIdx.x, g16 = g * 16;
  int h = blockIdx.y, lh = l*H_ + h;
  const unsigned short* Wlh = WcatT + (size_t)lh*1024*64;
  const float* biaslh = bias_e + (size_t)l*3072 + h*1024;

  int w = t >> 6, lane = t & 63, mr = lane & 15, q = lane >> 4;

  // P0: stage fea (16x64 f32 -> bf16), gate bias, gate-W2, zero accum
  {
    int row = t >> 5, c2 = (t & 31) * 2;
    float2 fv = *(const float2*)&fea[(size_t)(g16 + row)*64 + c2];
    *(unsigned int*)&feaS[row][c2] = f2bf2(fv.x, fv.y);
  }
  bs[t] = biaslh[t];                       // gate half: Pg bias | zeros
  if (t < 256) w2g[t] = mg_W2[lh*HID_ + t];
  #pragma unroll
  for (int s = 0; s < 3; ++s) {
    int idx = s*512 + t;
    if (idx < 16*68) ((float*)accum)[idx] = 0.f;
  }
  __syncthreads();

  // P1: gate-half PQ GEMM (8 waves x 64 cols)
  {
    int n0w = w * 64;
    short8 a0 = *(const short8*)&feaS[mr][q*8];
    short8 a1 = *(const short8*)&feaS[mr][32 + q*8];
    #pragma unroll
    for (int nt = 0; nt < 4; ++nt) {
      int n = n0w + nt*16 + mr;
      const unsigned short* bp = Wlh + (size_t)n*64 + q*8;
      short8 b0 = *(const short8*)bp;
      short8 b1 = *(const short8*)(bp + 32);
      f32x4 z = {0.f, 0.f, 0.f, 0.f};
      z = __builtin_amdgcn_mfma_f32_16x16x32_bf16(a0, b0, z, 0, 0, 0);
      z = __builtin_amdgcn_mfma_f32_16x16x32_bf16(a1, b1, z, 0, 0, 0);
      float bb = bs[n];
      #pragma unroll
      for (int r = 0; r < 4; ++r)
        PQs[q*4 + r][n] = f2bf(z[r] + bb);
    }
  }
  __syncthreads();

  // P2: gate dot (480 thr) + wp precompute (thr 480..495) + msg bias reload
  {
    float nb = biaslh[512 + t];            // msg half bias (Pm | zeros)
    if (t < 480) {
      int e = t >> 1, half = t & 1;
      int i = e / 15, jj = e - i*15;
      int j = (jj < i) ? jj : jj + 1;
      float s = 0.f;
      #pragma unroll
      for (int u = 0; u < 16; ++u) {
        int c = half*8 + u*16;
        short8 pv = *(const short8*)&PQs[i][c];
        short8 qv = *(const short8*)&PQs[j][256 + c];
        #pragma unroll
        for (int r = 0; r < 8; ++r) {
          float hv = selu_f(bf2f((unsigned short)pv[r]) + bf2f((unsigned short)qv[r]));
          s = fmaf(hv, w2g[c + r], s);
        }
      }
      gred[e][half] = s;
    } else if (t < 496) {
      wp[t - 480] = __powf(wts[g16 + (t - 480)], m_pow[lh]);
    }
    bs[t] = nb;
  }
  __syncthreads();

  // P3: msg-half PQ GEMM (overwrite PQs) + softmax (t<16)
  {
    int n0w = w * 64;
    short8 a0 = *(const short8*)&feaS[mr][q*8];
    short8 a1 = *(const short8*)&feaS[mr][32 + q*8];
    #pragma unroll
    for (int nt = 0; nt < 4; ++nt) {
      int n = n0w + nt*16 + mr;
      const unsigned short* bp = Wlh + (size_t)(512 + n)*64 + q*8;
      short8 b0 = *(const short8*)bp;
      short8 b1 = *(const short8*)(bp + 32);
      f32x4 z = {0.f, 0.f, 0.f, 0.f};
      z = __builtin_amdgcn_mfma_f32_16x16x32_bf16(a0, b0, z, 0, 0, 0);
      z = __builtin_amdgcn_mfma_f32_16x16x32_bf16(a1, b1, z, 0, 0, 0);
      float bb = bs[n];
      #pragma unroll
      for (int r = 0; r < 4; ++r)
        PQs[q*4 + r][n] = f2bf(z[r] + bb);
    }
  }
  if (t < 16) {
    int i = t;
    float b2v = mg_b2[lh];
    float gl[15];
    float m = -1e30f;
    #pragma unroll
    for (int jj = 0; jj < 15; ++jj) {
      float v = gred[i*15 + jj][0] + gred[i*15 + jj][1] + b2v;
      gl[jj] = v; m = fmaxf(m, v);
    }
    float den = 0.f;
    #pragma unroll
    for (int jj = 0; jj < 15; ++jj) {
      int j = (jj < i) ? jj : jj + 1;
      float x = wp[j] * __expf(gl[jj] - m);
      gl[jj] = x; den += x;
    }
    den += 1e-10f;
    float sa = 0.f;
    #pragma unroll
    for (int jj = 0; jj < 15; ++jj) {
      float a = gl[jj] / den; gateA[i*15 + jj] = a; sa += a;
    }
    sumat[i] = sa;
  }
  __syncthreads();

  // P4: msg MFMA: 15 m-tiles over 8 waves (2 per wave, last masked)
  f32x4 acc[2][4];
  #pragma unroll
  for (int mi = 0; mi < 2; ++mi)
    #pragma unroll
    for (int nt = 0; nt < 4; ++nt) { f32x4 z = {0.f,0.f,0.f,0.f}; acc[mi][nt] = z; }
  int iL[2], jL[2];
  #pragma unroll
  for (int mi = 0; mi < 2; ++mi) {
    int mt = w*2 + mi; if (mt > 14) mt = 14;
    int e = mt*16 + mr;
    int i = e / 15, jj = e - i*15;
    iL[mi] = i; jL[mi] = (jj < i) ? jj : jj + 1;
  }
  const unsigned short* W2lh = W2T + (size_t)lh*64*256;

  for (int kc = 0; kc < 8; ++kc) {
    int k0 = kc*32 + q*8;
    short8 bfr[4];
    #pragma unroll
    for (int nt = 0; nt < 4; ++nt)
      bfr[nt] = *(const short8*)&W2lh[(size_t)(nt*16 + mr)*256 + k0];
    #pragma unroll
    for (int mi = 0; mi < 2; ++mi) {
      if (w*2 + mi < 15) {
        short8 pv = *(const short8*)&PQs[iL[mi]][k0];
        short8 qv = *(const short8*)&PQs[jL[mi]][256 + k0];
        float hv[8];
        #pragma unroll
        for (int r = 0; r < 8; ++r)
          hv[r] = selu_f(bf2f((unsigned short)pv[r]) + bf2f((unsigned short)qv[r]));
        unsigned int apk[4];
        #pragma unroll
        for (int r2 = 0; r2 < 4; ++r2) apk[r2] = f2bf2(hv[2*r2], hv[2*r2+1]);
        short8 a = *reinterpret_cast<short8*>(apk);
        #pragma unroll
        for (int nt = 0; nt < 4; ++nt)
          acc[mi][nt] = __builtin_amdgcn_mfma_f32_16x16x32_bf16(a, bfr[nt], acc[mi][nt], 0, 0, 0);
      }
    }
  }
  // attn-weighted accumulate
  #pragma unroll
  for (int mi = 0; mi < 2; ++mi) {
    if (w*2 + mi < 15) {
      int ebase = (w*2 + mi)*16 + q*4;
      #pragma unroll
      for (int nt = 0; nt < 4; ++nt) {
        int f = nt*16 + mr;
        int icur = ebase / 15; float vsum = 0.f;
        #pragma unroll
        for (int r = 0; r < 4; ++r) {
          int e = ebase + r;
          int ie = e / 15;
          float v = acc[mi][nt][r] * gateA[e];
          if (ie != icur) { atomicAdd(&accum[icur][f], vsum); vsum = 0.f; icur = ie; }
          vsum += v;
        }
        atomicAdd(&accum[icur][f], vsum);
      }
    }
  }
  __syncthreads();
  #pragma unroll
  for (int s2 = 0; s2 < 2; ++s2) {
    int u = s2*512 + t;
    int i = u >> 6, f = u & 63;
    float val = (accum[i][f] + mm_b2[lh*F_ + f]*sumat[i]) * (1.f/3.f);
    atomicAdd(&fea_nxt[(size_t)(g16 + i)*64 + f], val);
  }
}

// ---------------------------------------------------------------------------
// Crystal phase, fully fused incl. PQ GEMM (f32 pre-acts, bias folded).
// ---------------------------------------------------------------------------
__global__ __launch_bounds__(256) void cry_fused(
    const float* __restrict__ fea, const unsigned short* __restrict__ WcryT,
    const float* __restrict__ bias_c, const unsigned short* __restrict__ W2cT,
    const float* __restrict__ cg_W2, const float* __restrict__ cg_b2,
    const float* __restrict__ cm_b2, const float* __restrict__ c_pow,
    const float* __restrict__ wts, float* __restrict__ out) {
  __shared__ __align__(16) unsigned short feaS[16][72];
  __shared__ float PQh[16][520];
  __shared__ float bsc[512];
  __shared__ float gred[16][18];
  __shared__ float attnL[16];
  __shared__ float sumatS;
  __shared__ __align__(16) unsigned short hidc[16][264];
  __shared__ float outg[64];
  int t = threadIdx.x;
  int g = blockIdx.x, g16 = g*16;
  {
    int row = t >> 4, c4 = (t & 15) * 4;
    float4 fv = *(const float4*)&fea[(size_t)(g16 + row)*64 + c4];
    *(unsigned int*)&feaS[row][c4]   = f2bf2(fv.x, fv.y);
    *(unsigned int*)&feaS[row][c4+2] = f2bf2(fv.z, fv.w);
  }
  if (t < 64) outg[t] = 0.f;
  int w = t >> 6, lane = t & 63, mr = lane & 15, q = lane >> 4;

  for (int h = 0; h < H_; ++h) {
    __syncthreads();
    bsc[t] = bias_c[h*512 + t];
    bsc[256 + t] = bias_c[h*512 + 256 + t];
    __syncthreads();
    {
      int n0w = w * 128;
      short8 a0 = *(const short8*)&feaS[mr][q*8];
      short8 a1 = *(const short8*)&feaS[mr][32 + q*8];
      #pragma unroll
      for (int nt = 0; nt < 8; ++nt) {
        int n = n0w + nt*16 + mr;
        const unsigned short* bp = WcryT + (size_t)(h*512 + n)*64 + q*8;
        short8 b0 = *(const short8*)bp;
        short8 b1 = *(const short8*)(bp + 32);
        f32x4 z = {0.f, 0.f, 0.f, 0.f};
        z = __builtin_amdgcn_mfma_f32_16x16x32_bf16(a0, b0, z, 0, 0, 0);
        z = __builtin_amdgcn_mfma_f32_16x16x32_bf16(a1, b1, z, 0, 0, 0);
        float bb = bsc[n];
        #pragma unroll
        for (int r = 0; r < 4; ++r)
          PQh[q*4 + r][n] = z[r] + bb;
      }
    }
    __syncthreads();
    {
      int i = t >> 4, c0 = (t & 15) * 16;
      float s = 0.f;
      #pragma unroll
      for (int c = c0; c < c0+16; ++c)
        s = fmaf(selu_f(PQh[i][c]), cg_W2[h*HID_ + c], s);
      gred[i][t & 15] = s;
    }
    __syncthreads();
    if (t < 16) {
      float sg = 0.f;
      #pragma unroll
      for (int u2 = 0; u2 < 16; ++u2) sg += gred[t][u2];
      gred[t][16] = sg + cg_b2[h];
    }
    __syncthreads();
    if (t == 0) {
      float pw = c_pow[h];
      float m = -1e30f;
      #pragma unroll
      for (int i = 0; i < 16; ++i) m = fmaxf(m, gred[i][16]);
      float den = 0.f; float v[16];
      #pragma unroll
      for (int i = 0; i < 16; ++i) {
        float x = __powf(wts[g16+i], pw) * __expf(gred[i][16] - m);
        v[i] = x; den += x;
      }
      den += 1e-10f;
      float sa = 0.f;
      #pragma unroll
      for (int i = 0; i < 16; ++i) { float a = v[i]/den; attnL[i] = a; sa += a; }
      sumatS = sa;
    }
    {
      int i = t >> 4, c0 = (t & 15) * 16;
      #pragma unroll
      for (int c = c0; c < c0+16; c += 2) {
        unsigned int pk = f2bf2(selu_f(PQh[i][256 + c]), selu_f(PQh[i][256 + c + 1]));
        *(unsigned int*)&hidc[i][c] = pk;
      }
    }
    __syncthreads();
    f32x4 acc = {0.f, 0.f, 0.f, 0.f};
    #pragma unroll
    for (int kc = 0; kc < 8; ++kc) {
      short8 a = *(const short8*)&hidc[mr][kc*32 + q*8];
      short8 b = *(const short8*)&W2cT[((size_t)h*64 + w*16 + mr)*HID_ + kc*32 + q*8];
      acc = __builtin_amdgcn_mfma_f32_16x16x32_bf16(a, b, acc, 0, 0, 0);
    }
    float p = 0.f;
    #pragma unroll
    for (int r = 0; r < 4; ++r) p = fmaf(attnL[q*4+r], acc[r], p);
    atomicAdd(&outg[w*16+mr], p);
    if (q == 0) atomicAdd(&outg[w*16+mr], cm_b2[h*F_ + w*16 + mr]*sumatS);
  }
  __syncthreads();
  if (t < 64) out[(size_t)g*64 + t] = outg[t] * (1.f/(float)H_);
}

extern "C" void kernel_launch(void* const* d_in, const int* in_sizes, int n_in,
                              void* d_out, int out_size, void* d_ws, size_t ws_size,
                              hipStream_t stream) {
  const float* elem_weights = (const float*)d_in[0];
  const float* elem_fea_in  = (const float*)d_in[1];
  const float* W_init = (const float*)d_in[2];
  const float* b_init = (const float*)d_in[3];
  const float* mg_W1  = (const float*)d_in[4];
  const float* mg_b1  = (const float*)d_in[5];
  const float* mg_W2  = (const float*)d_in[6];
  const float* mg_b2  = (const float*)d_in[7];
  const float* mm_W1  = (const float*)d_in[8];
  const float* mm_b1  = (const float*)d_in[9];
  const float* mm_W2  = (const float*)d_in[10];
  const float* mm_b2  = (const float*)d_in[11];
  const float* m_pow  = (const float*)d_in[12];
  const float* cg_W1  = (const float*)d_in[13];
  const float* cg_b1  = (const float*)d_in[14];
  const float* cg_W2  = (const float*)d_in[15];
  const float* cg_b2  = (const float*)d_in[16];
  const float* cm_W1  = (const float*)d_in[17];
  const float* cm_b1  = (const float*)d_in[18];
  const float* cm_W2  = (const float*)d_in[19];
  const float* cm_b2  = (const float*)d_in[20];
  const float* c_pow  = (const float*)d_in[21];

  float* ws = (float*)d_ws;
  float* feaA  = ws;
  float* feaB  = feaA + (size_t)N_*F_;
  unsigned short* WcatT = (unsigned short*)(feaB + (size_t)N_*F_);  // 9*1024*64
  unsigned short* W2mT  = WcatT + (size_t)9*1024*64;                // 9*64*256
  unsigned short* WcryT = W2mT  + (size_t)9*64*256;                 // 1536*64
  unsigned short* W2cT  = WcryT + (size_t)1536*64;                  // 3*64*256
  float* bias_e = (float*)(W2cT + (size_t)3*64*256);                // 3*3072
  float* bias_c = bias_e + 3*3072;                                  // 1536

  prep_wcat<<<(9*1024*64)/256, 256, 0, stream>>>(mg_W1, mm_W1, WcatT);
  prep_w2mt<<<(9*64*256)/256, 256, 0, stream>>>(mm_W2, W2mT);
  prep_wcry<<<(1536*64)/256, 256, 0, stream>>>(cg_W1, cm_W1, WcryT);
  prep_w2c<<<(3*64*256)/256, 256, 0, stream>>>(cm_W2, W2cT);
  prep_bias<<<(9216+1536+255)/256, 256, 0, stream>>>(mg_b1, mm_b1, cg_b1, cm_b1, bias_e, bias_c);
  init_embed<<<N_, 64, 0, stream>>>(elem_fea_in, W_init, b_init, elem_weights, feaA);

  float* cur = feaA; float* nxt = feaB;
  for (int l = 0; l < L_; ++l) {
    copy_fea<<<(N_*F_/4)/256, 256, 0, stream>>>(cur, nxt);
    edge_fused<<<dim3(G_, H_), 512, 0, stream>>>(
        cur, WcatT, bias_e, W2mT, mg_W2, mg_b2, m_pow, mm_b2,
        elem_weights, nxt, l);
    float* t = cur; cur = nxt; nxt = t;
  }

  cry_fused<<<G_, 256, 0, stream>>>(
      cur, WcryT, bias_c, W2cT, cg_W2, cg_b2, cm_b2, c_pow,
      elem_weights, (float*)d_out);
}

// Round 14
// 327.178 us; speedup vs baseline: 1.0888x; 1.0888x over previous
//
#include <hip/hip_runtime.h>
#include <hip/hip_bf16.h>

#define G_ 256
#define K_ 16
#define L_ 3
#define H_ 3
#define F_ 64
#define EMB_ 200
#define HID_ 256
#define N_ (G_*K_)          // 4096 nodes
#define E_ (G_*K_*(K_-1))   // 61440 edges

typedef __attribute__((ext_vector_type(8))) short short8;
typedef __attribute__((ext_vector_type(4))) float f32x4;

#define SELU_S 1.0507009873554804934193349852946f
#define SELU_SA (1.0507009873554804934193349852946f*1.6732632423543772848170429916717f)

// 5-op selu
__device__ __forceinline__ float selu_f(float x) {
  float e = __expf(x);
  float neg = fmaf(SELU_SA, e, -SELU_SA);
  float pos = SELU_S * x;
  return x > 0.f ? pos : neg;
}

__device__ __forceinline__ unsigned short f2bf(float x) {
  __hip_bfloat16 h = __float2bfloat16(x);
  return *reinterpret_cast<unsigned short*>(&h);
}

__device__ __forceinline__ unsigned int f2bf2(float a, float b) {
  float2 t; t.x = a; t.y = b;
  __hip_bfloat162 h = __float22bfloat162_rn(t);
  return *reinterpret_cast<unsigned int*>(&h);
}

__device__ __forceinline__ float bf2f(unsigned short u) {
  union { unsigned int i; float f; } v;
  v.i = ((unsigned int)u) << 16;
  return v.f;
}

// fea[n, 0:63] = elem_fea_in[n,:] @ W_init + b_init ; fea[n,63] = w[n]
__global__ __launch_bounds__(64) void init_embed(
    const float* __restrict__ fea_in, const float* __restrict__ W,
    const float* __restrict__ b, const float* __restrict__ wts,
    float* __restrict__ fea) {
  __shared__ float row[EMB_];
  int n = blockIdx.x;
  int j = threadIdx.x;
  for (int k = j; k < EMB_; k += 64) row[k] = fea_in[(size_t)n*EMB_ + k];
  __syncthreads();
  if (j < F_-1) {
    float s = b[j];
    for (int k = 0; k < EMB_; ++k) s = fmaf(row[k], W[k*(F_-1) + j], s);
    fea[(size_t)n*F_ + j] = s;
  } else {
    fea[(size_t)n*F_ + (F_-1)] = wts[n];
  }
}

// WcatT[lh][n][k] (bf16, n-major)
__global__ __launch_bounds__(256) void prep_wcat(
    const float* __restrict__ mg_W1, const float* __restrict__ mm_W1,
    unsigned short* __restrict__ WcatT) {
  int idx = blockIdx.x*256 + threadIdx.x;   // 9*1024*64
  int lh = idx >> 16;
  int n  = (idx >> 6) & 1023;
  int k  = idx & 63;
  const float* W = (n < 512) ? mg_W1 : mm_W1;
  int nn = n & 511;
  int r  = (nn < 256) ? k : (64 + k);
  int c  = nn & 255;
  WcatT[idx] = f2bf(W[(size_t)lh*(2*F_*HID_) + r*HID_ + c]);
}

// W2mT[lh][f][k] = bf16(mm_W2[lh][k][f])
__global__ __launch_bounds__(256) void prep_w2mt(
    const float* __restrict__ mm_W2, unsigned short* __restrict__ W2mT) {
  int idx = blockIdx.x*256 + threadIdx.x;   // 9*64*256
  int lh = idx >> 14;
  int f  = (idx >> 8) & 63;
  int k  = idx & 255;
  W2mT[idx] = f2bf(mm_W2[(size_t)lh*(HID_*F_) + k*F_ + f]);
}

// WcryT[n][k] (bf16, n-major, 1536 x 64)
__global__ __launch_bounds__(256) void prep_wcry(
    const float* __restrict__ cg_W1, const float* __restrict__ cm_W1,
    unsigned short* __restrict__ WcryT) {
  int idx = blockIdx.x*256 + threadIdx.x;   // 1536*64
  int n = idx >> 6, k = idx & 63;
  int h = n >> 9, r = n & 511;
  float v = (r < 256) ? cg_W1[(size_t)h*F_*HID_ + k*HID_ + r]
                      : cm_W1[(size_t)h*F_*HID_ + k*HID_ + (r - 256)];
  WcryT[idx] = f2bf(v);
}

// W2cT[h][f][k] = bf16(cm_W2[h][k][f])
__global__ __launch_bounds__(256) void prep_w2c(
    const float* __restrict__ cm_W2, unsigned short* __restrict__ W2cT) {
  int idx = blockIdx.x*256 + threadIdx.x;   // 3*64*256
  int h = idx >> 14;
  int f = (idx >> 8) & 63;
  int k = idx & 255;
  W2cT[idx] = f2bf(cm_W2[(size_t)h*HID_*F_ + k*F_ + f]);
}

// bias_e[l][3072]: h*1024 + [0,256)=mg_b1 ; [512,768)=mm_b1 ; else 0
// bias_c[1536]:    h*512  + [0,256)=cg_b1 ; [256,512)=cm_b1
__global__ __launch_bounds__(256) void prep_bias(
    const float* __restrict__ mg_b1, const float* __restrict__ mm_b1,
    const float* __restrict__ cg_b1, const float* __restrict__ cm_b1,
    float* __restrict__ bias_e, float* __restrict__ bias_c) {
  int idx = blockIdx.x*256 + threadIdx.x;
  if (idx < 9216) {
    int l = idx / 3072, c = idx - l*3072;
    int h = c >> 10, cc = c & 1023;
    int lh = l*H_ + h;
    float v = 0.f;
    if (cc < 256) v = mg_b1[lh*HID_ + cc];
    else if (cc >= 512 && cc < 768) v = mm_b1[lh*HID_ + (cc - 512)];
    bias_e[idx] = v;
  } else if (idx < 9216 + 1536) {
    int c = idx - 9216;
    int h = c >> 9, cc = c & 511;
    bias_c[c] = (cc < 256) ? cg_b1[h*HID_ + cc] : cm_b1[h*HID_ + (cc - 256)];
  }
}

// fea_nxt = cur (f32 copy, float4)
__global__ __launch_bounds__(256) void copy_fea(
    const float* __restrict__ in, float* __restrict__ out) {
  int i = blockIdx.x*256 + threadIdx.x;
  ((float4*)out)[i] = ((const float4*)in)[i];
}

// ---------------------------------------------------------------------------
// Fully fused edge phase, 512 threads, grid (G_, H_). LDS ~29 KB.
// launch_bounds(512,4): R13's (512,8) forced VGPR<=64 -> compiler spilled
// (VGPR=32, WRITE 22MB). With 4, compiler uses ~40 VGPR (R12) which still
// permits 8 waves/SIMD by the VGPR pool; LDS 29.7KB*4 < 160KB -> 4 blk/CU.
// ---------------------------------------------------------------------------
__global__ __launch_bounds__(512, 4) void edge_fused(
    const float* __restrict__ fea, const unsigned short* __restrict__ WcatT,
    const float* __restrict__ bias_e, const unsigned short* __restrict__ W2T,
    const float* __restrict__ mg_W2, const float* __restrict__ mg_b2,
    const float* __restrict__ m_pow, const float* __restrict__ mm_b2,
    const float* __restrict__ wts, float* __restrict__ fea_nxt, int l) {
  __shared__ __align__(16) unsigned short feaS[16][72];
  __shared__ __align__(16) unsigned short PQs[16][520];  // P|Q halves x256, skew 8
  __shared__ float bs[512];
  __shared__ float w2g[256];
  __shared__ float gred[240][2];
  __shared__ float gateA[240];
  __shared__ float accum[16][68];
  __shared__ float sumat[16];
  __shared__ float wp[16];
  int t = threadIdx.x;
  int g = blockIdx.x, g16 = g * 16;
  int h = blockIdx.y, lh = l*H_ + h;
  const unsigned short* Wlh = WcatT + (size_t)lh*1024*64;
  const float* biaslh = bias_e + (size_t)l*3072 + h*1024;

  int w = t >> 6, lane = t & 63, mr = lane & 15, q = lane >> 4;

  // P0: stage fea (16x64 f32 -> bf16), gate bias, gate-W2, zero accum
  {
    int row = t >> 5, c2 = (t & 31) * 2;
    float2 fv = *(const float2*)&fea[(size_t)(g16 + row)*64 + c2];
    *(unsigned int*)&feaS[row][c2] = f2bf2(fv.x, fv.y);
  }
  bs[t] = biaslh[t];                       // gate half: Pg bias | zeros
  if (t < 256) w2g[t] = mg_W2[lh*HID_ + t];
  #pragma unroll
  for (int s = 0; s < 3; ++s) {
    int idx = s*512 + t;
    if (idx < 16*68) ((float*)accum)[idx] = 0.f;
  }
  __syncthreads();

  // P1: gate-half PQ GEMM (8 waves x 64 cols)
  {
    int n0w = w * 64;
    short8 a0 = *(const short8*)&feaS[mr][q*8];
    short8 a1 = *(const short8*)&feaS[mr][32 + q*8];
    #pragma unroll
    for (int nt = 0; nt < 4; ++nt) {
      int n = n0w + nt*16 + mr;
      const unsigned short* bp = Wlh + (size_t)n*64 + q*8;
      short8 b0 = *(const short8*)bp;
      short8 b1 = *(const short8*)(bp + 32);
      f32x4 z = {0.f, 0.f, 0.f, 0.f};
      z = __builtin_amdgcn_mfma_f32_16x16x32_bf16(a0, b0, z, 0, 0, 0);
      z = __builtin_amdgcn_mfma_f32_16x16x32_bf16(a1, b1, z, 0, 0, 0);
      float bb = bs[n];
      #pragma unroll
      for (int r = 0; r < 4; ++r)
        PQs[q*4 + r][n] = f2bf(z[r] + bb);
    }
  }
  __syncthreads();

  // P2: gate dot (480 thr) + wp precompute (thr 480..495) + msg bias reload
  {
    float nb = biaslh[512 + t];            // msg half bias (Pm | zeros)
    if (t < 480) {
      int e = t >> 1, half = t & 1;
      int i = e / 15, jj = e - i*15;
      int j = (jj < i) ? jj : jj + 1;
      float s = 0.f;
      #pragma unroll
      for (int u = 0; u < 16; ++u) {
        int c = half*8 + u*16;
        short8 pv = *(const short8*)&PQs[i][c];
        short8 qv = *(const short8*)&PQs[j][256 + c];
        #pragma unroll
        for (int r = 0; r < 8; ++r) {
          float hv = selu_f(bf2f((unsigned short)pv[r]) + bf2f((unsigned short)qv[r]));
          s = fmaf(hv, w2g[c + r], s);
        }
      }
      gred[e][half] = s;
    } else if (t < 496) {
      wp[t - 480] = __powf(wts[g16 + (t - 480)], m_pow[lh]);
    }
    bs[t] = nb;
  }
  __syncthreads();

  // P3: msg-half PQ GEMM (overwrite PQs) + softmax (t<16)
  {
    int n0w = w * 64;
    short8 a0 = *(const short8*)&feaS[mr][q*8];
    short8 a1 = *(const short8*)&feaS[mr][32 + q*8];
    #pragma unroll
    for (int nt = 0; nt < 4; ++nt) {
      int n = n0w + nt*16 + mr;
      const unsigned short* bp = Wlh + (size_t)(512 + n)*64 + q*8;
      short8 b0 = *(const short8*)bp;
      short8 b1 = *(const short8*)(bp + 32);
      f32x4 z = {0.f, 0.f, 0.f, 0.f};
      z = __builtin_amdgcn_mfma_f32_16x16x32_bf16(a0, b0, z, 0, 0, 0);
      z = __builtin_amdgcn_mfma_f32_16x16x32_bf16(a1, b1, z, 0, 0, 0);
      float bb = bs[n];
      #pragma unroll
      for (int r = 0; r < 4; ++r)
        PQs[q*4 + r][n] = f2bf(z[r] + bb);
    }
  }
  if (t < 16) {
    int i = t;
    float b2v = mg_b2[lh];
    float gl[15];
    float m = -1e30f;
    #pragma unroll
    for (int jj = 0; jj < 15; ++jj) {
      float v = gred[i*15 + jj][0] + gred[i*15 + jj][1] + b2v;
      gl[jj] = v; m = fmaxf(m, v);
    }
    float den = 0.f;
    #pragma unroll
    for (int jj = 0; jj < 15; ++jj) {
      int j = (jj < i) ? jj : jj + 1;
      float x = wp[j] * __expf(gl[jj] - m);
      gl[jj] = x; den += x;
    }
    den += 1e-10f;
    float sa = 0.f;
    #pragma unroll
    for (int jj = 0; jj < 15; ++jj) {
      float a = gl[jj] / den; gateA[i*15 + jj] = a; sa += a;
    }
    sumat[i] = sa;
  }
  __syncthreads();

  // P4: msg MFMA: 15 m-tiles over 8 waves (2 per wave, last masked)
  f32x4 acc[2][4];
  #pragma unroll
  for (int mi = 0; mi < 2; ++mi)
    #pragma unroll
    for (int nt = 0; nt < 4; ++nt) { f32x4 z = {0.f,0.f,0.f,0.f}; acc[mi][nt] = z; }
  int iL[2], jL[2];
  #pragma unroll
  for (int mi = 0; mi < 2; ++mi) {
    int mt = w*2 + mi; if (mt > 14) mt = 14;
    int e = mt*16 + mr;
    int i = e / 15, jj = e - i*15;
    iL[mi] = i; jL[mi] = (jj < i) ? jj : jj + 1;
  }
  const unsigned short* W2lh = W2T + (size_t)lh*64*256;

  for (int kc = 0; kc < 8; ++kc) {
    int k0 = kc*32 + q*8;
    short8 bfr[4];
    #pragma unroll
    for (int nt = 0; nt < 4; ++nt)
      bfr[nt] = *(const short8*)&W2lh[(size_t)(nt*16 + mr)*256 + k0];
    #pragma unroll
    for (int mi = 0; mi < 2; ++mi) {
      if (w*2 + mi < 15) {
        short8 pv = *(const short8*)&PQs[iL[mi]][k0];
        short8 qv = *(const short8*)&PQs[jL[mi]][256 + k0];
        float hv[8];
        #pragma unroll
        for (int r = 0; r < 8; ++r)
          hv[r] = selu_f(bf2f((unsigned short)pv[r]) + bf2f((unsigned short)qv[r]));
        unsigned int apk[4];
        #pragma unroll
        for (int r2 = 0; r2 < 4; ++r2) apk[r2] = f2bf2(hv[2*r2], hv[2*r2+1]);
        short8 a = *reinterpret_cast<short8*>(apk);
        #pragma unroll
        for (int nt = 0; nt < 4; ++nt)
          acc[mi][nt] = __builtin_amdgcn_mfma_f32_16x16x32_bf16(a, bfr[nt], acc[mi][nt], 0, 0, 0);
      }
    }
  }
  // attn-weighted accumulate
  #pragma unroll
  for (int mi = 0; mi < 2; ++mi) {
    if (w*2 + mi < 15) {
      int ebase = (w*2 + mi)*16 + q*4;
      #pragma unroll
      for (int nt = 0; nt < 4; ++nt) {
        int f = nt*16 + mr;
        int icur = ebase / 15; float vsum = 0.f;
        #pragma unroll
        for (int r = 0; r < 4; ++r) {
          int e = ebase + r;
          int ie = e / 15;
          float v = acc[mi][nt][r] * gateA[e];
          if (ie != icur) { atomicAdd(&accum[icur][f], vsum); vsum = 0.f; icur = ie; }
          vsum += v;
        }
        atomicAdd(&accum[icur][f], vsum);
      }
    }
  }
  __syncthreads();
  #pragma unroll
  for (int s2 = 0; s2 < 2; ++s2) {
    int u = s2*512 + t;
    int i = u >> 6, f = u & 63;
    float val = (accum[i][f] + mm_b2[lh*F_ + f]*sumat[i]) * (1.f/3.f);
    atomicAdd(&fea_nxt[(size_t)(g16 + i)*64 + f], val);
  }
}

// ---------------------------------------------------------------------------
// Crystal phase, fully fused incl. PQ GEMM (f32 pre-acts, bias folded).
// ---------------------------------------------------------------------------
__global__ __launch_bounds__(256) void cry_fused(
    const float* __restrict__ fea, const unsigned short* __restrict__ WcryT,
    const float* __restrict__ bias_c, const unsigned short* __restrict__ W2cT,
    const float* __restrict__ cg_W2, const float* __restrict__ cg_b2,
    const float* __restrict__ cm_b2, const float* __restrict__ c_pow,
    const float* __restrict__ wts, float* __restrict__ out) {
  __shared__ __align__(16) unsigned short feaS[16][72];
  __shared__ float PQh[16][520];
  __shared__ float bsc[512];
  __shared__ float gred[16][18];
  __shared__ float attnL[16];
  __shared__ float sumatS;
  __shared__ __align__(16) unsigned short hidc[16][264];
  __shared__ float outg[64];
  int t = threadIdx.x;
  int g = blockIdx.x, g16 = g*16;
  {
    int row = t >> 4, c4 = (t & 15) * 4;
    float4 fv = *(const float4*)&fea[(size_t)(g16 + row)*64 + c4];
    *(unsigned int*)&feaS[row][c4]   = f2bf2(fv.x, fv.y);
    *(unsigned int*)&feaS[row][c4+2] = f2bf2(fv.z, fv.w);
  }
  if (t < 64) outg[t] = 0.f;
  int w = t >> 6, lane = t & 63, mr = lane & 15, q = lane >> 4;

  for (int h = 0; h < H_; ++h) {
    __syncthreads();
    bsc[t] = bias_c[h*512 + t];
    bsc[256 + t] = bias_c[h*512 + 256 + t];
    __syncthreads();
    {
      int n0w = w * 128;
      short8 a0 = *(const short8*)&feaS[mr][q*8];
      short8 a1 = *(const short8*)&feaS[mr][32 + q*8];
      #pragma unroll
      for (int nt = 0; nt < 8; ++nt) {
        int n = n0w + nt*16 + mr;
        const unsigned short* bp = WcryT + (size_t)(h*512 + n)*64 + q*8;
        short8 b0 = *(const short8*)bp;
        short8 b1 = *(const short8*)(bp + 32);
        f32x4 z = {0.f, 0.f, 0.f, 0.f};
        z = __builtin_amdgcn_mfma_f32_16x16x32_bf16(a0, b0, z, 0, 0, 0);
        z = __builtin_amdgcn_mfma_f32_16x16x32_bf16(a1, b1, z, 0, 0, 0);
        float bb = bsc[n];
        #pragma unroll
        for (int r = 0; r < 4; ++r)
          PQh[q*4 + r][n] = z[r] + bb;
      }
    }
    __syncthreads();
    {
      int i = t >> 4, c0 = (t & 15) * 16;
      float s = 0.f;
      #pragma unroll
      for (int c = c0; c < c0+16; ++c)
        s = fmaf(selu_f(PQh[i][c]), cg_W2[h*HID_ + c], s);
      gred[i][t & 15] = s;
    }
    __syncthreads();
    if (t < 16) {
      float sg = 0.f;
      #pragma unroll
      for (int u2 = 0; u2 < 16; ++u2) sg += gred[t][u2];
      gred[t][16] = sg + cg_b2[h];
    }
    __syncthreads();
    if (t == 0) {
      float pw = c_pow[h];
      float m = -1e30f;
      #pragma unroll
      for (int i = 0; i < 16; ++i) m = fmaxf(m, gred[i][16]);
      float den = 0.f; float v[16];
      #pragma unroll
      for (int i = 0; i < 16; ++i) {
        float x = __powf(wts[g16+i], pw) * __expf(gred[i][16] - m);
        v[i] = x; den += x;
      }
      den += 1e-10f;
      float sa = 0.f;
      #pragma unroll
      for (int i = 0; i < 16; ++i) { float a = v[i]/den; attnL[i] = a; sa += a; }
      sumatS = sa;
    }
    {
      int i = t >> 4, c0 = (t & 15) * 16;
      #pragma unroll
      for (int c = c0; c < c0+16; c += 2) {
        unsigned int pk = f2bf2(selu_f(PQh[i][256 + c]), selu_f(PQh[i][256 + c + 1]));
        *(unsigned int*)&hidc[i][c] = pk;
      }
    }
    __syncthreads();
    f32x4 acc = {0.f, 0.f, 0.f, 0.f};
    #pragma unroll
    for (int kc = 0; kc < 8; ++kc) {
      short8 a = *(const short8*)&hidc[mr][kc*32 + q*8];
      short8 b = *(const short8*)&W2cT[((size_t)h*64 + w*16 + mr)*HID_ + kc*32 + q*8];
      acc = __builtin_amdgcn_mfma_f32_16x16x32_bf16(a, b, acc, 0, 0, 0);
    }
    float p = 0.f;
    #pragma unroll
    for (int r = 0; r < 4; ++r) p = fmaf(attnL[q*4+r], acc[r], p);
    atomicAdd(&outg[w*16+mr], p);
    if (q == 0) atomicAdd(&outg[w*16+mr], cm_b2[h*F_ + w*16 + mr]*sumatS);
  }
  __syncthreads();
  if (t < 64) out[(size_t)g*64 + t] = outg[t] * (1.f/(float)H_);
}

extern "C" void kernel_launch(void* const* d_in, const int* in_sizes, int n_in,
                              void* d_out, int out_size, void* d_ws, size_t ws_size,
                              hipStream_t stream) {
  const float* elem_weights = (const float*)d_in[0];
  const float* elem_fea_in  = (const float*)d_in[1];
  const float* W_init = (const float*)d_in[2];
  const float* b_init = (const float*)d_in[3];
  const float* mg_W1  = (const float*)d_in[4];
  const float* mg_b1  = (const float*)d_in[5];
  const float* mg_W2  = (const float*)d_in[6];
  const float* mg_b2  = (const float*)d_in[7];
  const float* mm_W1  = (const float*)d_in[8];
  const float* mm_b1  = (const float*)d_in[9];
  const float* mm_W2  = (const float*)d_in[10];
  const float* mm_b2  = (const float*)d_in[11];
  const float* m_pow  = (const float*)d_in[12];
  const float* cg_W1  = (const float*)d_in[13];
  const float* cg_b1  = (const float*)d_in[14];
  const float* cg_W2  = (const float*)d_in[15];
  const float* cg_b2  = (const float*)d_in[16];
  const float* cm_W1  = (const float*)d_in[17];
  const float* cm_b1  = (const float*)d_in[18];
  const float* cm_W2  = (const float*)d_in[19];
  const float* cm_b2  = (const float*)d_in[20];
  const float* c_pow  = (const float*)d_in[21];

  float* ws = (float*)d_ws;
  float* feaA  = ws;
  float* feaB  = feaA + (size_t)N_*F_;
  unsigned short* WcatT = (unsigned short*)(feaB + (size_t)N_*F_);  // 9*1024*64
  unsigned short* W2mT  = WcatT + (size_t)9*1024*64;                // 9*64*256
  unsigned short* WcryT = W2mT  + (size_t)9*64*256;                 // 1536*64
  unsigned short* W2cT  = WcryT + (size_t)1536*64;                  // 3*64*256
  float* bias_e = (float*)(W2cT + (size_t)3*64*256);                // 3*3072
  float* bias_c = bias_e + 3*3072;                                  // 1536

  prep_wcat<<<(9*1024*64)/256, 256, 0, stream>>>(mg_W1, mm_W1, WcatT);
  prep_w2mt<<<(9*64*256)/256, 256, 0, stream>>>(mm_W2, W2mT);
  prep_wcry<<<(1536*64)/256, 256, 0, stream>>>(cg_W1, cm_W1, WcryT);
  prep_w2c<<<(3*64*256)/256, 256, 0, stream>>>(cm_W2, W2cT);
  prep_bias<<<(9216+1536+255)/256, 256, 0, stream>>>(mg_b1, mm_b1, cg_b1, cm_b1, bias_e, bias_c);
  init_embed<<<N_, 64, 0, stream>>>(elem_fea_in, W_init, b_init, elem_weights, feaA);

  float* cur = feaA; float* nxt = feaB;
  for (int l = 0; l < L_; ++l) {
    copy_fea<<<(N_*F_/4)/256, 256, 0, stream>>>(cur, nxt);
    edge_fused<<<dim3(G_, H_), 512, 0, stream>>>(
        cur, WcatT, bias_e, W2mT, mg_W2, mg_b2, m_pow, mm_b2,
        elem_weights, nxt, l);
    float* t = cur; cur = nxt; nxt = t;
  }

  cry_fused<<<G_, 256, 0, stream>>>(
      cur, WcryT, bias_c, W2cT, cg_W2, cg_b2, cm_b2, c_pow,
      elem_weights, (float*)d_out);
}

// Round 17
// 323.686 us; speedup vs baseline: 1.1006x; 1.0108x over previous
//
#include <hip/hip_runtime.h>
#include <hip/hip_bf16.h>

#define G_ 256
#define K_ 16
#define L_ 3
#define H_ 3
#define F_ 64
#define EMB_ 200
#define HID_ 256
#define N_ (G_*K_)

typedef __attribute__((ext_vector_type(8))) short short8;
typedef __attribute__((ext_vector_type(4))) float f32x4;

#define SELU_S 1.0507009873554804934193349852946f
#define SELU_SA (1.0507009873554804934193349852946f*1.6732632423543772848170429916717f)

__device__ __forceinline__ float selu_f(float x) {
  float e = __expf(x);
  float neg = fmaf(SELU_SA, e, -SELU_SA);
  float pos = SELU_S * x;
  return x > 0.f ? pos : neg;
}

__device__ __forceinline__ unsigned short f2bf(float x) {
  __hip_bfloat16 h = __float2bfloat16(x);
  return *reinterpret_cast<unsigned short*>(&h);
}

__device__ __forceinline__ unsigned int f2bf2(float a, float b) {
  float2 t; t.x = a; t.y = b;
  __hip_bfloat162 h = __float22bfloat162_rn(t);
  return *reinterpret_cast<unsigned int*>(&h);
}

__device__ __forceinline__ float bf2f(unsigned short u) {
  union { unsigned int i; float f; } v;
  v.i = ((unsigned int)u) << 16;
  return v.f;
}

// fea[n, 0:63] = elem_fea_in[n,:] @ W_init + b_init ; fea[n,63] = w[n]
__global__ __launch_bounds__(64) void init_embed(
    const float* __restrict__ fea_in, const float* __restrict__ W,
    const float* __restrict__ b, const float* __restrict__ wts,
    float* __restrict__ fea) {
  __shared__ float row[EMB_];
  int n = blockIdx.x;
  int j = threadIdx.x;
  for (int k = j; k < EMB_; k += 64) row[k] = fea_in[(size_t)n*EMB_ + k];
  __syncthreads();
  if (j < F_-1) {
    float s = b[j];
    for (int k = 0; k < EMB_; ++k) s = fmaf(row[k], W[k*(F_-1) + j], s);
    fea[(size_t)n*F_ + j] = s;
  } else {
    fea[(size_t)n*F_ + (F_-1)] = wts[n];
  }
}

// One grid-strided kernel: all bf16 weight transposes + bias folding.
__global__ __launch_bounds__(256) void prep_all(
    const float* __restrict__ mg_W1, const float* __restrict__ mm_W1,
    const float* __restrict__ mm_W2, const float* __restrict__ cg_W1,
    const float* __restrict__ cm_W1, const float* __restrict__ cm_W2,
    const float* __restrict__ mg_b1, const float* __restrict__ mm_b1,
    const float* __restrict__ cg_b1, const float* __restrict__ cm_b1,
    unsigned short* __restrict__ WcatT, unsigned short* __restrict__ W2mT,
    unsigned short* __restrict__ WcryT, unsigned short* __restrict__ W2cT,
    float* __restrict__ bias_e, float* __restrict__ bias_c) {
  int gt = blockIdx.x*256 + threadIdx.x, GT = gridDim.x*256;
  for (int idx = gt; idx < 9*1024*64; idx += GT) {      // WcatT[lh][n][k]
    int lh = idx >> 16, n = (idx >> 6) & 1023, k = idx & 63;
    const float* W = (n < 512) ? mg_W1 : mm_W1;
    int nn = n & 511;
    int r = (nn < 256) ? k : (64 + k);
    WcatT[idx] = f2bf(W[(size_t)lh*(2*F_*HID_) + r*HID_ + (nn & 255)]);
  }
  for (int idx = gt; idx < 9*64*256; idx += GT) {       // W2mT[lh][f][k]
    int lh = idx >> 14, f = (idx >> 8) & 63, k = idx & 255;
    W2mT[idx] = f2bf(mm_W2[(size_t)lh*(HID_*F_) + k*F_ + f]);
  }
  for (int idx = gt; idx < 1536*64; idx += GT) {        // WcryT[n][k]
    int n = idx >> 6, k = idx & 63;
    int hh = n >> 9, r = n & 511;
    float v = (r < 256) ? cg_W1[(size_t)hh*F_*HID_ + k*HID_ + r]
                        : cm_W1[(size_t)hh*F_*HID_ + k*HID_ + (r - 256)];
    WcryT[idx] = f2bf(v);
  }
  for (int idx = gt; idx < 3*64*256; idx += GT) {       // W2cT[h][f][k]
    int hh = idx >> 14, f = (idx >> 8) & 63, k = idx & 255;
    W2cT[idx] = f2bf(cm_W2[(size_t)hh*HID_*F_ + k*F_ + f]);
  }
  for (int idx = gt; idx < 9216 + 1536; idx += GT) {    // folded biases
    if (idx < 9216) {
      int l = idx / 3072, c = idx - l*3072;
      int hh = c >> 10, cc = c & 1023;
      int lh = l*H_ + hh;
      float v = 0.f;
      if (cc < 256) v = mg_b1[lh*HID_ + cc];
      else if (cc >= 512 && cc < 768) v = mm_b1[lh*HID_ + (cc - 512)];
      bias_e[idx] = v;
    } else {
      int c = idx - 9216;
      int hh = c >> 9, cc = c & 511;
      bias_c[c] = (cc < 256) ? cg_b1[hh*HID_ + cc] : cm_b1[hh*HID_ + (cc - 256)];
    }
  }
}

// fea_nxt = cur (f32 copy, float4)
__global__ __launch_bounds__(256) void copy_fea(
    const float* __restrict__ in, float* __restrict__ out) {
  int i = blockIdx.x*256 + threadIdx.x;
  ((float4*)out)[i] = ((const float4*)in)[i];
}

// ---------------------------------------------------------------------------
// Fused edge phase (proven R14 structure), 512 threads, grid (G_, H_).
// Two-pass PQ GEMM over one 16x512 LDS buffer; LDS ~29 KB; VGPR ~40.
// ---------------------------------------------------------------------------
__global__ __launch_bounds__(512, 4) void edge_fused(
    const float* __restrict__ fea, const unsigned short* __restrict__ WcatT,
    const float* __restrict__ bias_e, const unsigned short* __restrict__ W2T,
    const float* __restrict__ mg_W2, const float* __restrict__ mg_b2,
    const float* __restrict__ m_pow, const float* __restrict__ mm_b2,
    const float* __restrict__ wts, float* __restrict__ fea_nxt, int l) {
  __shared__ __align__(16) unsigned short feaS[16][72];
  __shared__ __align__(16) unsigned short PQs[16][520];
  __shared__ float bs[512];
  __shared__ float w2g[256];
  __shared__ float gred[240][2];
  __shared__ float gateA[240];
  __shared__ float accum[16][68];
  __shared__ float sumat[16];
  __shared__ float wp[16];
  int t = threadIdx.x;
  int g = blockIdx.x, g16 = g * 16;
  int h = blockIdx.y, lh = l*H_ + h;
  const unsigned short* Wlh = WcatT + (size_t)lh*1024*64;
  const float* biaslh = bias_e + (size_t)l*3072 + h*1024;
  int w = t >> 6, lane = t & 63, mr = lane & 15, q = lane >> 4;

  // P0: stage fea (bf16), gate bias, gate-W2, zero accum
  {
    int row = t >> 5, c2 = (t & 31) * 2;
    float2 fv = *(const float2*)&fea[(size_t)(g16 + row)*64 + c2];
    *(unsigned int*)&feaS[row][c2] = f2bf2(fv.x, fv.y);
  }
  bs[t] = biaslh[t];
  if (t < 256) w2g[t] = mg_W2[lh*HID_ + t];
  #pragma unroll
  for (int s = 0; s < 3; ++s) {
    int idx = s*512 + t;
    if (idx < 16*68) ((float*)accum)[idx] = 0.f;
  }
  __syncthreads();

  // P1: gate-half PQ GEMM (8 waves x 64 cols)
  {
    int n0w = w * 64;
    short8 a0 = *(const short8*)&feaS[mr][q*8];
    short8 a1 = *(const short8*)&feaS[mr][32 + q*8];
    #pragma unroll
    for (int nt = 0; nt < 4; ++nt) {
      int n = n0w + nt*16 + mr;
      const unsigned short* bp = Wlh + (size_t)n*64 + q*8;
      short8 b0 = *(const short8*)bp;
      short8 b1 = *(const short8*)(bp + 32);
      f32x4 z = {0.f, 0.f, 0.f, 0.f};
      z = __builtin_amdgcn_mfma_f32_16x16x32_bf16(a0, b0, z, 0, 0, 0);
      z = __builtin_amdgcn_mfma_f32_16x16x32_bf16(a1, b1, z, 0, 0, 0);
      float bb = bs[n];
      #pragma unroll
      for (int r = 0; r < 4; ++r)
        PQs[q*4 + r][n] = f2bf(z[r] + bb);
    }
  }
  __syncthreads();

  // P2: gate dot (480 thr) + wp precompute + msg bias reload
  {
    float nb = biaslh[512 + t];
    if (t < 480) {
      int e = t >> 1, half = t & 1;
      int i = e / 15, jj = e - i*15;
      int j = (jj < i) ? jj : jj + 1;
      float s = 0.f;
      #pragma unroll
      for (int u = 0; u < 16; ++u) {
        int c = half*8 + u*16;
        short8 pv = *(const short8*)&PQs[i][c];
        short8 qv = *(const short8*)&PQs[j][256 + c];
        #pragma unroll
        for (int r = 0; r < 8; ++r) {
          float hv = selu_f(bf2f((unsigned short)pv[r]) + bf2f((unsigned short)qv[r]));
          s = fmaf(hv, w2g[c + r], s);
        }
      }
      gred[e][half] = s;
    } else if (t < 496) {
      wp[t - 480] = __powf(wts[g16 + (t - 480)], m_pow[lh]);
    }
    bs[t] = nb;
  }
  __syncthreads();

  // P3: msg-half PQ GEMM (overwrite PQs) + softmax (t<16)
  {
    int n0w = w * 64;
    short8 a0 = *(const short8*)&feaS[mr][q*8];
    short8 a1 = *(const short8*)&feaS[mr][32 + q*8];
    #pragma unroll
    for (int nt = 0; nt < 4; ++nt) {
      int n = n0w + nt*16 + mr;
      const unsigned short* bp = Wlh + (size_t)(512 + n)*64 + q*8;
      short8 b0 = *(const short8*)bp;
      short8 b1 = *(const short8*)(bp + 32);
      f32x4 z = {0.f, 0.f, 0.f, 0.f};
      z = __builtin_amdgcn_mfma_f32_16x16x32_bf16(a0, b0, z, 0, 0, 0);
      z = __builtin_amdgcn_mfma_f32_16x16x32_bf16(a1, b1, z, 0, 0, 0);
      float bb = bs[n];
      #pragma unroll
      for (int r = 0; r < 4; ++r)
        PQs[q*4 + r][n] = f2bf(z[r] + bb);
    }
  }
  if (t < 16) {
    int i = t;
    float b2v = mg_b2[lh];
    float gl[15];
    float m = -1e30f;
    #pragma unroll
    for (int jj = 0; jj < 15; ++jj) {
      float v = gred[i*15 + jj][0] + gred[i*15 + jj][1] + b2v;
      gl[jj] = v; m = fmaxf(m, v);
    }
    float den = 0.f;
    #pragma unroll
    for (int jj = 0; jj < 15; ++jj) {
      int j = (jj < i) ? jj : jj + 1;
      float x = wp[j] * __expf(gl[jj] - m);
      gl[jj] = x; den += x;
    }
    den += 1e-10f;
    float sa = 0.f;
    #pragma unroll
    for (int jj = 0; jj < 15; ++jj) {
      float a = gl[jj] / den; gateA[i*15 + jj] = a; sa += a;
    }
    sumat[i] = sa;
  }
  __syncthreads();

  // P4: msg MFMA (15 m-tiles over 8 waves) + attn-weighted accum
  f32x4 acc[2][4];
  #pragma unroll
  for (int mi = 0; mi < 2; ++mi)
    #pragma unroll
    for (int nt = 0; nt < 4; ++nt) { f32x4 z = {0.f,0.f,0.f,0.f}; acc[mi][nt] = z; }
  int iL[2], jL[2];
  #pragma unroll
  for (int mi = 0; mi < 2; ++mi) {
    int mt = w*2 + mi; if (mt > 14) mt = 14;
    int e = mt*16 + mr;
    int i = e / 15, jj = e - i*15;
    iL[mi] = i; jL[mi] = (jj < i) ? jj : jj + 1;
  }
  const unsigned short* W2lh = W2T + (size_t)lh*64*256;

  for (int kc = 0; kc < 8; ++kc) {
    int k0 = kc*32 + q*8;
    short8 bfr[4];
    #pragma unroll
    for (int nt = 0; nt < 4; ++nt)
      bfr[nt] = *(const short8*)&W2lh[(size_t)(nt*16 + mr)*256 + k0];
    #pragma unroll
    for (int mi = 0; mi < 2; ++mi) {
      if (w*2 + mi < 15) {
        short8 pv = *(const short8*)&PQs[iL[mi]][k0];
        short8 qv = *(const short8*)&PQs[jL[mi]][256 + k0];
        float hv[8];
        #pragma unroll
        for (int r = 0; r < 8; ++r)
          hv[r] = selu_f(bf2f((unsigned short)pv[r]) + bf2f((unsigned short)qv[r]));
        unsigned int apk[4];
        #pragma unroll
        for (int r2 = 0; r2 < 4; ++r2) apk[r2] = f2bf2(hv[2*r2], hv[2*r2+1]);
        short8 a = *reinterpret_cast<short8*>(apk);
        #pragma unroll
        for (int nt = 0; nt < 4; ++nt)
          acc[mi][nt] = __builtin_amdgcn_mfma_f32_16x16x32_bf16(a, bfr[nt], acc[mi][nt], 0, 0, 0);
      }
    }
  }
  #pragma unroll
  for (int mi = 0; mi < 2; ++mi) {
    if (w*2 + mi < 15) {
      int ebase = (w*2 + mi)*16 + q*4;
      #pragma unroll
      for (int nt = 0; nt < 4; ++nt) {
        int f = nt*16 + mr;
        int icur = ebase / 15; float vsum = 0.f;
        #pragma unroll
        for (int r = 0; r < 4; ++r) {
          int e = ebase + r;
          int ie = e / 15;
          float v = acc[mi][nt][r] * gateA[e];
          if (ie != icur) { atomicAdd(&accum[icur][f], vsum); vsum = 0.f; icur = ie; }
          vsum += v;
        }
        atomicAdd(&accum[icur][f], vsum);
      }
    }
  }
  __syncthreads();
  #pragma unroll
  for (int s2 = 0; s2 < 2; ++s2) {
    int u = s2*512 + t;
    int i = u >> 6, f = u & 63;
    float val = (accum[i][f] + mm_b2[lh*F_ + f]*sumat[i]) * (1.f/3.f);
    atomicAdd(&fea_nxt[(size_t)(g16 + i)*64 + f], val);
  }
}

// ---------------------------------------------------------------------------
// Crystal phase, fully fused incl. PQ GEMM (f32 pre-acts, bias folded).
// ---------------------------------------------------------------------------
__global__ __launch_bounds__(256) void cry_fused(
    const float* __restrict__ fea, const unsigned short* __restrict__ WcryT,
    const float* __restrict__ bias_c, const unsigned short* __restrict__ W2cT,
    const float* __restrict__ cg_W2, const float* __restrict__ cg_b2,
    const float* __restrict__ cm_b2, const float* __restrict__ c_pow,
    const float* __restrict__ wts, float* __restrict__ out) {
  __shared__ __align__(16) unsigned short feaS[16][72];
  __shared__ float PQh[16][520];
  __shared__ float bsc[512];
  __shared__ float gred[16][18];
  __shared__ float attnL[16];
  __shared__ float sumatS;
  __shared__ __align__(16) unsigned short hidc[16][264];
  __shared__ float outg[64];
  int t = threadIdx.x;
  int g = blockIdx.x, g16 = g*16;
  {
    int row = t >> 4, c4 = (t & 15) * 4;
    float4 fv = *(const float4*)&fea[(size_t)(g16 + row)*64 + c4];
    *(unsigned int*)&feaS[row][c4]   = f2bf2(fv.x, fv.y);
    *(unsigned int*)&feaS[row][c4+2] = f2bf2(fv.z, fv.w);
  }
  if (t < 64) outg[t] = 0.f;
  int w = t >> 6, lane = t & 63, mr = lane & 15, q = lane >> 4;
  for (int h = 0; h < H_; ++h) {
    __syncthreads();
    bsc[t] = bias_c[h*512 + t];
    bsc[256 + t] = bias_c[h*512 + 256 + t];
    __syncthreads();
    {
      int n0w = w * 128;
      short8 a0 = *(const short8*)&feaS[mr][q*8];
      short8 a1 = *(const short8*)&feaS[mr][32 + q*8];
      #pragma unroll
      for (int nt = 0; nt < 8; ++nt) {
        int n = n0w + nt*16 + mr;
        const unsigned short* bp = WcryT + (size_t)(h*512 + n)*64 + q*8;
        short8 b0 = *(const short8*)bp;
        short8 b1 = *(const short8*)(bp + 32);
        f32x4 z = {0.f, 0.f, 0.f, 0.f};
        z = __builtin_amdgcn_mfma_f32_16x16x32_bf16(a0, b0, z, 0, 0, 0);
        z = __builtin_amdgcn_mfma_f32_16x16x32_bf16(a1, b1, z, 0, 0, 0);
        float bb = bsc[n];
        #pragma unroll
        for (int r = 0; r < 4; ++r)
          PQh[q*4 + r][n] = z[r] + bb;
      }
    }
    __syncthreads();
    {
      int i = t >> 4, c0 = (t & 15) * 16;
      float s = 0.f;
      #pragma unroll
      for (int c = c0; c < c0+16; ++c)
        s = fmaf(selu_f(PQh[i][c]), cg_W2[h*HID_ + c], s);
      gred[i][t & 15] = s;
    }
    __syncthreads();
    if (t < 16) {
      float sg = 0.f;
      #pragma unroll
      for (int u2 = 0; u2 < 16; ++u2) sg += gred[t][u2];
      gred[t][16] = sg + cg_b2[h];
    }
    __syncthreads();
    if (t == 0) {
      float pw = c_pow[h];
      float m = -1e30f;
      #pragma unroll
      for (int i = 0; i < 16; ++i) m = fmaxf(m, gred[i][16]);
      float den = 0.f; float v[16];
      #pragma unroll
      for (int i = 0; i < 16; ++i) {
        float x = __powf(wts[g16+i], pw) * __expf(gred[i][16] - m);
        v[i] = x; den += x;
      }
      den += 1e-10f;
      float sa = 0.f;
      #pragma unroll
      for (int i = 0; i < 16; ++i) { float a = v[i]/den; attnL[i] = a; sa += a; }
      sumatS = sa;
    }
    {
      int i = t >> 4, c0 = (t & 15) * 16;
      #pragma unroll
      for (int c = c0; c < c0+16; c += 2) {
        unsigned int pk = f2bf2(selu_f(PQh[i][256 + c]), selu_f(PQh[i][256 + c + 1]));
        *(unsigned int*)&hidc[i][c] = pk;
      }
    }
    __syncthreads();
    f32x4 acc = {0.f, 0.f, 0.f, 0.f};
    #pragma unroll
    for (int kc = 0; kc < 8; ++kc) {
      short8 a = *(const short8*)&hidc[mr][kc*32 + q*8];
      short8 b = *(const short8*)&W2cT[((size_t)h*64 + w*16 + mr)*HID_ + kc*32 + q*8];
      acc = __builtin_amdgcn_mfma_f32_16x16x32_bf16(a, b, acc, 0, 0, 0);
    }
    float p = 0.f;
    #pragma unroll
    for (int r = 0; r < 4; ++r) p = fmaf(attnL[q*4+r], acc[r], p);
    atomicAdd(&outg[w*16+mr], p);
    if (q == 0) atomicAdd(&outg[w*16+mr], cm_b2[h*F_ + w*16 + mr]*sumatS);
  }
  __syncthreads();
  if (t < 64) out[(size_t)g*64 + t] = outg[t] * (1.f/(float)H_);
}

extern "C" void kernel_launch(void* const* d_in, const int* in_sizes, int n_in,
                              void* d_out, int out_size, void* d_ws, size_t ws_size,
                              hipStream_t stream) {
  const float* elem_weights = (const float*)d_in[0];
  const float* elem_fea_in  = (const float*)d_in[1];
  const float* W_init = (const float*)d_in[2];
  const float* b_init = (const float*)d_in[3];
  const float* mg_W1  = (const float*)d_in[4];
  const float* mg_b1  = (const float*)d_in[5];
  const float* mg_W2  = (const float*)d_in[6];
  const float* mg_b2  = (const float*)d_in[7];
  const float* mm_W1  = (const float*)d_in[8];
  const float* mm_b1  = (const float*)d_in[9];
  const float* mm_W2  = (const float*)d_in[10];
  const float* mm_b2  = (const float*)d_in[11];
  const float* m_pow  = (const float*)d_in[12];
  const float* cg_W1  = (const float*)d_in[13];
  const float* cg_b1  = (const float*)d_in[14];
  const float* cg_W2  = (const float*)d_in[15];
  const float* cg_b2  = (const float*)d_in[16];
  const float* cm_W1  = (const float*)d_in[17];
  const float* cm_b1  = (const float*)d_in[18];
  const float* cm_W2  = (const float*)d_in[19];
  const float* cm_b2  = (const float*)d_in[20];
  const float* c_pow  = (const float*)d_in[21];
  float* out = (float*)d_out;

  float* ws = (float*)d_ws;
  float* feaA  = ws;
  float* feaB  = feaA + (size_t)N_*F_;
  unsigned short* WcatT = (unsigned short*)(feaB + (size_t)N_*F_);  // 9*1024*64
  unsigned short* W2mT  = WcatT + (size_t)9*1024*64;                // 9*64*256
  unsigned short* WcryT = W2mT  + (size_t)9*64*256;                 // 1536*64
  unsigned short* W2cT  = WcryT + (size_t)1536*64;                  // 3*64*256
  float* bias_e = (float*)(W2cT + (size_t)3*64*256);                // 9216
  float* bias_c = bias_e + 9216;                                    // 1536

  prep_all<<<128, 256, 0, stream>>>(mg_W1, mm_W1, mm_W2, cg_W1, cm_W1, cm_W2,
                                    mg_b1, mm_b1, cg_b1, cm_b1,
                                    WcatT, W2mT, WcryT, W2cT, bias_e, bias_c);
  init_embed<<<N_, 64, 0, stream>>>(elem_fea_in, W_init, b_init, elem_weights, feaA);

  float* cur = feaA; float* nxt = feaB;
  for (int l = 0; l < L_; ++l) {
    copy_fea<<<(N_*F_/4)/256, 256, 0, stream>>>(cur, nxt);
    edge_fused<<<dim3(G_, H_), 512, 0, stream>>>(
        cur, WcatT, bias_e, W2mT, mg_W2, mg_b2, m_pow, mm_b2,
        elem_weights, nxt, l);
    float* t = cur; cur = nxt; nxt = t;
  }

  cry_fused<<<G_, 256, 0, stream>>>(
      cur, WcryT, bias_c, W2cT, cg_W2, cg_b2, cm_b2, c_pow,
      elem_weights, out);
}